// Round 15
// baseline (193.668 us; speedup 1.0000x reference)
//
#include <hip/hip_runtime.h>
#include <hip/hip_bf16.h>
#include <stdint.h>

#define E_EXP 8
#define TOK   4096
#define HD    768
#define FD    3072
#define BK    64
#define CAP   8320   // 8192 assignments + max per-expert tile padding
#define NKP2  2      // GEMM2 split-K ways (R7/R11-proven; 3 regressed in R10)

typedef __attribute__((ext_vector_type(8))) short bf16x8;
typedef __attribute__((ext_vector_type(4))) float f32x4;

__device__ __forceinline__ unsigned short f2bf(float f) {
  union { float f; unsigned u; } v; v.f = f;
  unsigned r = v.u + 0x7fffu + ((v.u >> 16) & 1u);
  return (unsigned short)(r >> 16);
}
__device__ __forceinline__ float bf2f(unsigned short u) {
  union { unsigned u; float f; } v; v.u = ((unsigned)u) << 16;
  return v.f;
}

__device__ __forceinline__ void gload_lds16(const void* g, void* l) {
  __builtin_amdgcn_global_load_lds(
      (const __attribute__((address_space(1))) unsigned int*)g,
      (__attribute__((address_space(3))) unsigned int*)l, 16, 0, 0);
}

// bijective XCD-chunking swizzle (m204)
__device__ __forceinline__ int xcd_swizzle(int orig, int nwg) {
  int xcd = orig & 7, base = orig >> 3;
  int q = nwg >> 3, r = nwg & 7;
  return (xcd < r ? xcd * (q + 1) : r * (q + 1) + (xcd - r) * q) + base;
}

// ---------------- prep: weight transpose (blocks 0..9215) + router (tail) ------
// Data-independent paths merged to overlap router under the transpose stream.
// R14 lessons fixed here: (1) union LDS forced 24KB on all transpose blocks ->
// occupancy 50%; router now reads rw directly (coalesced 32B/lane, L2-resident)
// so kernel LDS = 8.7KB -> 8 blocks/CU. (2) transpose wrote 8 scalar u16/thread
// at 4-way bank conflict (5.5M cycles); now 4x b64 packed row-writes.
#define TT 64
#define T1_TILES (E_EXP * (FD / TT) * (HD / TT))   // 4608
#define T2_TILES (E_EXP * (HD / TT) * (FD / TT))   // 4608
#define ROUTER_BLOCKS (TOK / 4)                    // 1024
__global__ __launch_bounds__(256) void prep_kernel(
    const float* __restrict__ x, const float* __restrict__ rw,
    const float* __restrict__ rb, unsigned short* __restrict__ xb,
    float* __restrict__ probs, int* __restrict__ ids,
    float* __restrict__ gates,
    const float* __restrict__ w1, unsigned short* __restrict__ w1t,
    const float* __restrict__ w2, unsigned short* __restrict__ w2t)
{
  __shared__ unsigned short tile[TT][TT + 4];   // 8704 B (transpose path only)

  if (blockIdx.x >= T1_TILES + T2_TILES) {
    // ---------------- router path (no LDS, no barrier) ----------------
    const int wave = threadIdx.x >> 6, lane = threadIdx.x & 63;
    const int t = (blockIdx.x - (T1_TILES + T2_TILES)) * 4 + wave;
    const float* xrow = x + (size_t)t * HD;
    float acc[8] = {0, 0, 0, 0, 0, 0, 0, 0};
#pragma unroll
    for (int i = 0; i < HD / 64; ++i) {
      int h = i * 64 + lane;
      float xv = xrow[h];
      xb[(size_t)t * HD + h] = f2bf(xv);
      const float4* rp = (const float4*)&rw[h * 8];
      float4 r0 = rp[0], r1 = rp[1];
      acc[0] += xv * r0.x; acc[1] += xv * r0.y;
      acc[2] += xv * r0.z; acc[3] += xv * r0.w;
      acc[4] += xv * r1.x; acc[5] += xv * r1.y;
      acc[6] += xv * r1.z; acc[7] += xv * r1.w;
    }
#pragma unroll
    for (int d = 1; d < 64; d <<= 1) {
#pragma unroll
      for (int e = 0; e < 8; ++e) acc[e] += __shfl_xor(acc[e], d);
    }
    if (lane == 0) {
      float p[8]; float m = -1e30f, sum = 0.f;
#pragma unroll
      for (int e = 0; e < 8; ++e) { p[e] = acc[e] + rb[e]; m = fmaxf(m, p[e]); }
#pragma unroll
      for (int e = 0; e < 8; ++e) { p[e] = __expf(p[e] - m); sum += p[e]; }
      float inv = 1.f / sum;
#pragma unroll
      for (int e = 0; e < 8; ++e) p[e] *= inv;
      int i1 = 0;
#pragma unroll
      for (int e = 1; e < 8; ++e) if (p[e] > p[i1]) i1 = e;   // ties -> lower idx
      int i2 = (i1 == 0) ? 1 : 0;
#pragma unroll
      for (int e = 0; e < 8; ++e) if (e != i1 && p[e] > p[i2]) i2 = e;
      ids[t * 2] = i1; ids[t * 2 + 1] = i2;
      float den = 1.f / (p[i1] + p[i2] + 1e-9f);
      gates[t * 2] = p[i1] * den; gates[t * 2 + 1] = p[i2] * den;
#pragma unroll
      for (int e = 0; e < 8; ++e) probs[t * 8 + e] = p[e];
    }
    return;
  }

  // ---------------- transpose path: W[e][Kd][Nd] f32 -> Wt[e][Nd][Kd] bf16 ----
  int id = blockIdx.x;
  const float* W; unsigned short* Wt; int Kd, Nd;
  if (id < T1_TILES) {
    W = w1; Wt = w1t; Kd = HD; Nd = FD;
  } else {
    id -= T1_TILES; W = w2; Wt = w2t; Kd = FD; Nd = HD;
  }
  const int nx = Nd / TT, nk = Kd / TT;
  const int e = id / (nx * nk);
  const int rem = id % (nx * nk);
  const int n0 = (rem % nx) * TT, k0 = (rem / nx) * TT;

  // read: thread (kq = tid>>4, c4 = tid&15) loads 4 k-rows x 4 n (4x float4)
  const int c4 = threadIdx.x & 15, kq = threadIdx.x >> 4;
  float4 v[4];
#pragma unroll
  for (int j2 = 0; j2 < 4; ++j2) {
    int k = kq * 4 + j2;
    v[j2] = *(const float4*)&W[((size_t)e * Kd + k0 + k) * Nd + n0 + c4 * 4];
  }
  const float* vf = (const float*)v;   // vf[j2*4 + j] = W[k0+kq*4+j2][n0+c4*4+j]
  // write: 4x b64 (4 contiguous bf16 along k) per thread
#pragma unroll
  for (int j = 0; j < 4; ++j) {
    int row = c4 * 4 + j;
    unsigned long long pk =
        (unsigned long long)f2bf(vf[0 * 4 + j]) |
        ((unsigned long long)f2bf(vf[1 * 4 + j]) << 16) |
        ((unsigned long long)f2bf(vf[2 * 4 + j]) << 32) |
        ((unsigned long long)f2bf(vf[3 * 4 + j]) << 48);
    *(unsigned long long*)&tile[row][kq * 4] = pk;
  }
  __syncthreads();
  const int n = threadIdx.x >> 2, kc = threadIdx.x & 3;
  unsigned short* dst = Wt + ((size_t)e * Nd + n0 + n) * Kd + k0 + kc * 16;
  bf16x8 a = *(const bf16x8*)&tile[n][kc * 16];
  bf16x8 b = *(const bf16x8*)&tile[n][kc * 16 + 8];
  *(bf16x8*)&dst[0] = a;
  *(bf16x8*)&dst[8] = b;
}

// ---------------- fused stats+scatter (single block, 1024 threads) -------------
__global__ __launch_bounds__(1024) void stats_scatter_kernel(
    const int* __restrict__ ids, const float* __restrict__ probs,
    int* __restrict__ meta, int* __restrict__ token_list,
    int* __restrict__ pos_list, float* __restrict__ loss_out)
{
  __shared__ int cnt[8], top1c[8], cur[8];
  __shared__ float wsum[16][8];
  const int tid = threadIdx.x;
  if (tid < 8) { cnt[tid] = 0; top1c[tid] = 0; cur[tid] = 0; }
  __syncthreads();
  float local[8] = {0, 0, 0, 0, 0, 0, 0, 0};
  for (int t = tid; t < TOK; t += 1024) {
    int e0 = ids[2 * t], e1 = ids[2 * t + 1];
    atomicAdd(&cnt[e0], 1); atomicAdd(&cnt[e1], 1); atomicAdd(&top1c[e0], 1);
    const float4* pr = (const float4*)&probs[(size_t)t * 8];
    float4 a = pr[0], b = pr[1];
    local[0] += a.x; local[1] += a.y; local[2] += a.z; local[3] += a.w;
    local[4] += b.x; local[5] += b.y; local[6] += b.z; local[7] += b.w;
  }
#pragma unroll
  for (int d = 1; d < 64; d <<= 1) {
#pragma unroll
    for (int e = 0; e < 8; ++e) local[e] += __shfl_xor(local[e], d);
  }
  const int wave = tid >> 6, lane = tid & 63;
  if (lane == 0) {
#pragma unroll
    for (int e = 0; e < 8; ++e) wsum[wave][e] = local[e];
  }
  __syncthreads();
  if (tid == 0) {
    int total = 0, nt1 = 0;
    for (int e = 0; e < 8; ++e) {
      int c = cnt[e];
      meta[e] = c;
      meta[16 + e] = total;                     // base
      int t1 = (c + 127) >> 7;
      for (int i = 0; i < t1; ++i) { meta[64 + nt1 * 2] = e; meta[64 + nt1 * 2 + 1] = total + i * 128; ++nt1; }
      total += c;
    }
    meta[32] = nt1;
    float loss = 0.f;
    for (int e = 0; e < 8; ++e) {
      float psum = 0.f;
      for (int w = 0; w < 16; ++w) psum += wsum[w][e];
      loss += ((float)top1c[e] / 4096.f) * (psum / 4096.f);
    }
    loss_out[0] = 0.001f * loss;
  }
  __syncthreads();
  for (int t = tid; t < TOK; t += 1024) {
    int e0 = ids[2 * t], e1 = ids[2 * t + 1];
    int s0 = atomicAdd(&cur[e0], 1);
    int s1 = atomicAdd(&cur[e1], 1);
    int p0 = meta[16 + e0] + s0;
    int p1 = meta[16 + e1] + s1;
    token_list[p0] = t; pos_list[2 * t] = p0;
    token_list[p1] = t; pos_list[2 * t + 1] = p1;
  }
}

// ---------------- grouped GEMM, single-buffer 2-barrier loop (R7/R11 proven) ---
// MODE 0: x@w1 + relu^2 -> h1 bf16; MODE 1: h1@w2 (+b2 in kp0) -> h2 partials.
// NW waves (NW*64 thr), per-wave (BM/2) x (BN/(NW/2)). 1-D grid, decode
// wgid -> (mt, ny, kp) n/k-fastest + bijective XCD chunking. NKP split-K ways;
// partial kp writes Cout + kp*CAP*NN; bias only in kp==0.
// LDS: linear rows of BK=64 bf16; 16B k-chunks XOR-swizzled by (row&7) on BOTH
// the global source address (staging) and the ds_read address (rule 21).
// PINNED DECISIONS (each regressed when violated):
//  - min-waves hint = 4 (5 spilled acc to scratch: R9, WRITE 49->235MB)
//  - single-buffer 32KB LDS (explicit dbuf 64KB: R8 -50%; ring-3 144KB: R12 -47%)
//  - overlap comes from ~2.4 resident blocks/CU (m114), not source pipelining
template<int BM, int BN, int MODE, int NW, int NKP>
__global__ __launch_bounds__(NW * 64, 4) void moe_gemm(
    const unsigned short* __restrict__ A,
    const unsigned short* __restrict__ Bw,   // [E][NN][Kdim] bf16 (pre-transposed)
    const float* __restrict__ bias,          // [E][NN]
    const int* __restrict__ token_list,
    const int* __restrict__ meta,
    unsigned short* __restrict__ Cout,
    const int Kdim, const int NN)
{
  const int NY = NN / BN;
  const int wgid = xcd_swizzle(blockIdx.x, gridDim.x);
  const int mt = wgid / (NY * NKP);
  const int slot = wgid - mt * (NY * NKP);
  const int ny = slot % NY;
  const int kp = slot / NY;
  const int nt_total = meta[32];
  if (mt >= nt_total) return;
  const int* tmap = meta + 64;
  const int e = tmap[mt * 2], arow0 = tmap[mt * 2 + 1];
  const int ne_end = meta[16 + e] + meta[e];
  const int n0 = ny * BN;
  const int KLEN = Kdim / NKP;
  const int kbeg = kp * KLEN;
  unsigned short* Cp = Cout + (size_t)kp * CAP * NN;

  __shared__ unsigned short lA[BM * BK];
  __shared__ unsigned short lB[BN * BK];

  const int tid = threadIdx.x;
  const int wave = tid >> 6, lane = tid & 63;
  constexpr int WC_N = NW / 2;              // waves along N
  const int wr = wave / WC_N, wc = wave % WC_N;
  constexpr int WROWS = BM / 2;             // per-wave rows
  constexpr int WCOLS = BN / WC_N;          // per-wave cols
  constexpr int FM = WROWS / 16, FN = WCOLS / 16;
  constexpr int NCA = (BM / 8) / NW;        // A 1KB-chunks per wave
  constexpr int NCB = (BN / 8) / NW;        // B chunks per wave

  // swizzled k-offset for staging: logical chunk (lane&7) XOR row-in-8 (lane>>3)&7
  const int kswz = ((lane & 7) ^ ((lane >> 3) & 7)) * 8;

  size_t aSrc[NCA];
#pragma unroll
  for (int i = 0; i < NCA; ++i) {
    int c = wave + i * NW;
    int r = c * 8 + (lane >> 3);
    int grow = (MODE == 0) ? token_list[arow0 + r] : (arow0 + r);
    aSrc[i] = (size_t)grow * Kdim + kbeg + kswz;
  }
  size_t bSrc[NCB];
#pragma unroll
  for (int i = 0; i < NCB; ++i) {
    int c = wave + i * NW;
    int n = n0 + c * 8 + (lane >> 3);
    bSrc[i] = ((size_t)e * NN + n) * Kdim + kbeg + kswz;
  }

  f32x4 acc[FM][FN] = {};

  for (int k0 = 0; k0 < KLEN; k0 += BK) {
#pragma unroll
    for (int i = 0; i < NCA; ++i)
      gload_lds16(A + aSrc[i] + k0, &lA[(wave + i * NW) * 512]);
#pragma unroll
    for (int i = 0; i < NCB; ++i)
      gload_lds16(Bw + bSrc[i] + k0, &lB[(wave + i * NW) * 512]);
    __syncthreads();
#pragma unroll
    for (int kk = 0; kk < BK; kk += 32) {
      bf16x8 af[FM], bfr[FN];
      const int lc = (kk >> 3) + (lane >> 4);   // logical 16B-chunk index 0..7
#pragma unroll
      for (int m2 = 0; m2 < FM; ++m2) {
        int row = wr * WROWS + m2 * 16 + (lane & 15);
        af[m2] = *(const bf16x8*)&lA[row * BK + ((lc ^ (row & 7)) << 3)];
      }
#pragma unroll
      for (int n2 = 0; n2 < FN; ++n2) {
        int row = wc * WCOLS + n2 * 16 + (lane & 15);
        bfr[n2] = *(const bf16x8*)&lB[row * BK + ((lc ^ (row & 7)) << 3)];
      }
#pragma unroll
      for (int m2 = 0; m2 < FM; ++m2)
#pragma unroll
        for (int n2 = 0; n2 < FN; ++n2)
          acc[m2][n2] = __builtin_amdgcn_mfma_f32_16x16x32_bf16(
              af[m2], bfr[n2], acc[m2][n2], 0, 0, 0);
    }
    __syncthreads();
  }

  const float* be = bias + (size_t)e * NN;
#pragma unroll
  for (int m2 = 0; m2 < FM; ++m2) {
    const int lr = wr * WROWS + m2 * 16 + (lane >> 4) * 4;
#pragma unroll
    for (int n2 = 0; n2 < FN; ++n2) {
      const int col = n0 + wc * WCOLS + n2 * 16 + (lane & 15);
      const float bv = (kp == 0) ? be[col] : 0.f;
#pragma unroll
      for (int j = 0; j < 4; ++j) {
        const int arow = arow0 + lr + j;
        if (arow < ne_end) {
          float v = acc[m2][n2][j] + bv;
          if (MODE == 0) { v = fmaxf(v, 0.f); v = v * v; }
          Cp[(size_t)arow * NN + col] = f2bf(v);
        }
      }
    }
  }
}

// ---------------- combine: out[t] = sum_k gates * sum_kp h2_kp[pos] ------------
__global__ __launch_bounds__(256) void combine_kernel(
    const unsigned short* __restrict__ h2, const int* __restrict__ pos_list,
    const float* __restrict__ gates, float* __restrict__ out)
{
  const int wave = threadIdx.x >> 6, lane = threadIdx.x & 63;
  const int t = blockIdx.x * 4 + wave;
  const int p0 = pos_list[2 * t], p1 = pos_list[2 * t + 1];
  const float g0 = gates[2 * t], g1 = gates[2 * t + 1];
  float* o = out + (size_t)t * HD;
#pragma unroll
  for (int i = 0; i < 3; ++i) {
    int h = i * 256 + lane * 4;
    float4 o4 = {0.f, 0.f, 0.f, 0.f};
#pragma unroll
    for (int kp = 0; kp < NKP2; ++kp) {
      const unsigned short* base = h2 + (size_t)kp * CAP * HD;
      ushort4 a = *(const ushort4*)&base[(size_t)p0 * HD + h];
      ushort4 b = *(const ushort4*)&base[(size_t)p1 * HD + h];
      o4.x += g0 * bf2f(a.x) + g1 * bf2f(b.x);
      o4.y += g0 * bf2f(a.y) + g1 * bf2f(b.y);
      o4.z += g0 * bf2f(a.z) + g1 * bf2f(b.z);
      o4.w += g0 * bf2f(a.w) + g1 * bf2f(b.w);
    }
    *(float4*)&o[h] = o4;
  }
}

// -------------------------------- launch ---------------------------------------
extern "C" void kernel_launch(void* const* d_in, const int* in_sizes, int n_in,
                              void* d_out, int out_size, void* d_ws, size_t ws_size,
                              hipStream_t stream)
{
  (void)in_sizes; (void)n_in; (void)ws_size; (void)out_size;
  const float* x  = (const float*)d_in[0];
  const float* rw = (const float*)d_in[1];
  const float* rb = (const float*)d_in[2];
  const float* w1 = (const float*)d_in[3];
  const float* b1 = (const float*)d_in[4];
  const float* w2 = (const float*)d_in[5];
  const float* b2 = (const float*)d_in[6];
  float* out = (float*)d_out;

  char* ws = (char*)d_ws;
  size_t off = 0;
  auto alloc = [&](size_t bytes) {
    off = (off + 255) & ~(size_t)255;
    void* p = ws + off;
    off += bytes;
    return p;
  };
  unsigned short* xb  = (unsigned short*)alloc((size_t)TOK * HD * 2);
  unsigned short* w1t = (unsigned short*)alloc((size_t)E_EXP * FD * HD * 2);
  unsigned short* w2t = (unsigned short*)alloc((size_t)E_EXP * HD * FD * 2);
  unsigned short* h1  = (unsigned short*)alloc((size_t)CAP * FD * 2);
  unsigned short* h2  = (unsigned short*)alloc((size_t)NKP2 * CAP * HD * 2);  // k-partials
  int*   token_list = (int*)alloc(CAP * 4);
  int*   pos_list   = (int*)alloc((size_t)TOK * 2 * 4);
  int*   ids        = (int*)alloc((size_t)TOK * 2 * 4);
  float* gates      = (float*)alloc((size_t)TOK * 2 * 4);
  float* probs      = (float*)alloc((size_t)TOK * 8 * 4);
  int*   meta       = (int*)alloc(1024 * 4);
  char*  ctrl       = (char*)token_list;
  size_t ctrl_bytes = (ws + off) - ctrl;

  hipMemsetAsync(ctrl, 0, ctrl_bytes, stream);

  // prep: both weight transposes (9216 blocks) + router (1024 blocks), merged
  prep_kernel<<<T1_TILES + T2_TILES + ROUTER_BLOCKS, 256, 0, stream>>>(
      x, rw, rb, xb, probs, ids, gates, w1, w1t, w2, w2t);
  stats_scatter_kernel<<<1, 1024, 0, stream>>>(ids, probs, meta,
      token_list, pos_list, out + (size_t)TOK * HD);
  // GEMM1: 71 max m-tiles x 24 n-tiles, 4-wave blocks (64x64 per wave)
  moe_gemm<128, 128, 0, 4, 1><<<71 * (FD / 128), 256, 0, stream>>>(
      xb, w1t, b1, token_list, meta, h1, HD, FD);
  // GEMM2: 71 max m-tiles x 6 n-tiles x 2 k-splits (R7/R11-proven config)
  moe_gemm<128, 128, 1, 4, NKP2><<<71 * (HD / 128) * NKP2, 256, 0, stream>>>(
      h1, w2t, b2, token_list, meta, h2, FD, HD);
  combine_kernel<<<TOK / 4, 256, 0, stream>>>(h2, pos_list, gates, out);
}

// Round 16
// 193.041 us; speedup vs baseline: 1.0033x; 1.0033x over previous
//
#include <hip/hip_runtime.h>
#include <hip/hip_bf16.h>
#include <stdint.h>

#define E_EXP 8
#define TOK   4096
#define HD    768
#define FD    3072
#define BK    64
#define CAP   8704   // 8192 assignments + 255 max overhang for 256-row tiles
#define NKP2  2      // GEMM2 split-K ways (R7/R11-proven; 3 regressed in R10)

typedef __attribute__((ext_vector_type(8))) short bf16x8;
typedef __attribute__((ext_vector_type(4))) float f32x4;

__device__ __forceinline__ unsigned short f2bf(float f) {
  union { float f; unsigned u; } v; v.f = f;
  unsigned r = v.u + 0x7fffu + ((v.u >> 16) & 1u);
  return (unsigned short)(r >> 16);
}
__device__ __forceinline__ float bf2f(unsigned short u) {
  union { unsigned u; float f; } v; v.u = ((unsigned)u) << 16;
  return v.f;
}

__device__ __forceinline__ void gload_lds16(const void* g, void* l) {
  __builtin_amdgcn_global_load_lds(
      (const __attribute__((address_space(1))) unsigned int*)g,
      (__attribute__((address_space(3))) unsigned int*)l, 16, 0, 0);
}

// bijective XCD-chunking swizzle (m204)
__device__ __forceinline__ int xcd_swizzle(int orig, int nwg) {
  int xcd = orig & 7, base = orig >> 3;
  int q = nwg >> 3, r = nwg & 7;
  return (xcd < r ? xcd * (q + 1) : r * (q + 1) + (xcd - r) * q) + base;
}

// ---------------- prep: router (blocks 0..1023) + weight transpose (rest) ------
// R14-measured version (73us; R15's "fixes" were null->slightly worse).
#define TT 64
#define T1_TILES (E_EXP * (FD / TT) * (HD / TT))   // 4608
#define T2_TILES (E_EXP * (HD / TT) * (FD / TT))   // 4608
#define ROUTER_BLOCKS (TOK / 4)                    // 1024
__global__ __launch_bounds__(256) void prep_kernel(
    const float* __restrict__ x, const float* __restrict__ rw,
    const float* __restrict__ rb, unsigned short* __restrict__ xb,
    float* __restrict__ probs, int* __restrict__ ids,
    float* __restrict__ gates,
    const float* __restrict__ w1, unsigned short* __restrict__ w1t,
    const float* __restrict__ w2, unsigned short* __restrict__ w2t)
{
  __shared__ union {
    float lrw[E_EXP * HD];                  // router: [e][h], 24 KB
    unsigned short tile[TT][TT + 4];        // transpose: 8.7 KB
  } sh;

  if (blockIdx.x < ROUTER_BLOCKS) {
    // ---------------- router path ----------------
    for (int i = threadIdx.x; i < E_EXP * HD; i += 256) {
      int h = i >> 3, e = i & 7;
      sh.lrw[e * HD + h] = rw[i];
    }
    __syncthreads();
    const int wave = threadIdx.x >> 6, lane = threadIdx.x & 63;
    const int t = blockIdx.x * 4 + wave;
    const float* xrow = x + (size_t)t * HD;
    float acc[8] = {0, 0, 0, 0, 0, 0, 0, 0};
#pragma unroll
    for (int i = 0; i < HD / 64; ++i) {
      int h = i * 64 + lane;
      float xv = xrow[h];
      xb[(size_t)t * HD + h] = f2bf(xv);
#pragma unroll
      for (int e = 0; e < 8; ++e) acc[e] += xv * sh.lrw[e * HD + h];
    }
#pragma unroll
    for (int d = 1; d < 64; d <<= 1) {
#pragma unroll
      for (int e = 0; e < 8; ++e) acc[e] += __shfl_xor(acc[e], d);
    }
    if (lane == 0) {
      float p[8]; float m = -1e30f, sum = 0.f;
#pragma unroll
      for (int e = 0; e < 8; ++e) { p[e] = acc[e] + rb[e]; m = fmaxf(m, p[e]); }
#pragma unroll
      for (int e = 0; e < 8; ++e) { p[e] = __expf(p[e] - m); sum += p[e]; }
      float inv = 1.f / sum;
#pragma unroll
      for (int e = 0; e < 8; ++e) p[e] *= inv;
      int i1 = 0;
#pragma unroll
      for (int e = 1; e < 8; ++e) if (p[e] > p[i1]) i1 = e;   // ties -> lower idx
      int i2 = (i1 == 0) ? 1 : 0;
#pragma unroll
      for (int e = 0; e < 8; ++e) if (e != i1 && p[e] > p[i2]) i2 = e;
      ids[t * 2] = i1; ids[t * 2 + 1] = i2;
      float den = 1.f / (p[i1] + p[i2] + 1e-9f);
      gates[t * 2] = p[i1] * den; gates[t * 2 + 1] = p[i2] * den;
#pragma unroll
      for (int e = 0; e < 8; ++e) probs[t * 8 + e] = p[e];
    }
    return;
  }

  // ---------------- transpose path ----------------
  int id = blockIdx.x - ROUTER_BLOCKS;
  const float* W; unsigned short* Wt; int Kd, Nd;
  if (id < T1_TILES) {
    W = w1; Wt = w1t; Kd = HD; Nd = FD;
  } else {
    id -= T1_TILES; W = w2; Wt = w2t; Kd = FD; Nd = HD;
  }
  const int nx = Nd / TT, nk = Kd / TT;
  const int e = id / (nx * nk);
  const int rem = id % (nx * nk);
  const int n0 = (rem % nx) * TT, k0 = (rem / nx) * TT;

  const int r0 = threadIdx.x >> 4;        // 0..15
  const int c4 = threadIdx.x & 15;        // float4 index within 64-wide row
#pragma unroll
  for (int i = 0; i < 4; ++i) {
    int kk = r0 + i * 16;
    float4 v = *(const float4*)&W[((size_t)e * Kd + k0 + kk) * Nd + n0 + c4 * 4];
    sh.tile[c4 * 4 + 0][kk] = f2bf(v.x);
    sh.tile[c4 * 4 + 1][kk] = f2bf(v.y);
    sh.tile[c4 * 4 + 2][kk] = f2bf(v.z);
    sh.tile[c4 * 4 + 3][kk] = f2bf(v.w);
  }
  __syncthreads();
  const int n = threadIdx.x >> 2, kc = threadIdx.x & 3;
  unsigned short* dst = Wt + ((size_t)e * Nd + n0 + n) * Kd + k0 + kc * 16;
  bf16x8 a = *(const bf16x8*)&sh.tile[n][kc * 16];
  bf16x8 b = *(const bf16x8*)&sh.tile[n][kc * 16 + 8];
  *(bf16x8*)&dst[0] = a;
  *(bf16x8*)&dst[8] = b;
}

// ---------------- fused stats+scatter (single block, 1024 threads) -------------
// Builds BOTH tile maps: 128-row map @ meta[64] (count meta[32], for GEMM2) and
// 256-row map @ meta[512] (count meta[33], for GEMM1).
__global__ __launch_bounds__(1024) void stats_scatter_kernel(
    const int* __restrict__ ids, const float* __restrict__ probs,
    int* __restrict__ meta, int* __restrict__ token_list,
    int* __restrict__ pos_list, float* __restrict__ loss_out)
{
  __shared__ int cnt[8], top1c[8], cur[8];
  __shared__ float wsum[16][8];
  const int tid = threadIdx.x;
  if (tid < 8) { cnt[tid] = 0; top1c[tid] = 0; cur[tid] = 0; }
  __syncthreads();
  float local[8] = {0, 0, 0, 0, 0, 0, 0, 0};
  for (int t = tid; t < TOK; t += 1024) {
    int e0 = ids[2 * t], e1 = ids[2 * t + 1];
    atomicAdd(&cnt[e0], 1); atomicAdd(&cnt[e1], 1); atomicAdd(&top1c[e0], 1);
    const float4* pr = (const float4*)&probs[(size_t)t * 8];
    float4 a = pr[0], b = pr[1];
    local[0] += a.x; local[1] += a.y; local[2] += a.z; local[3] += a.w;
    local[4] += b.x; local[5] += b.y; local[6] += b.z; local[7] += b.w;
  }
#pragma unroll
  for (int d = 1; d < 64; d <<= 1) {
#pragma unroll
    for (int e = 0; e < 8; ++e) local[e] += __shfl_xor(local[e], d);
  }
  const int wave = tid >> 6, lane = tid & 63;
  if (lane == 0) {
#pragma unroll
    for (int e = 0; e < 8; ++e) wsum[wave][e] = local[e];
  }
  __syncthreads();
  if (tid == 0) {
    int total = 0, nt1 = 0, nt2 = 0;
    for (int e = 0; e < 8; ++e) {
      int c = cnt[e];
      meta[e] = c;
      meta[16 + e] = total;                     // base
      int t1 = (c + 127) >> 7;
      for (int i = 0; i < t1; ++i) { meta[64 + nt1 * 2] = e; meta[64 + nt1 * 2 + 1] = total + i * 128; ++nt1; }
      int t2 = (c + 255) >> 8;
      for (int i = 0; i < t2; ++i) { meta[512 + nt2 * 2] = e; meta[512 + nt2 * 2 + 1] = total + i * 256; ++nt2; }
      total += c;
    }
    meta[32] = nt1; meta[33] = nt2;
    float loss = 0.f;
    for (int e = 0; e < 8; ++e) {
      float psum = 0.f;
      for (int w = 0; w < 16; ++w) psum += wsum[w][e];
      loss += ((float)top1c[e] / 4096.f) * (psum / 4096.f);
    }
    loss_out[0] = 0.001f * loss;
  }
  __syncthreads();
  for (int t = tid; t < TOK; t += 1024) {
    int e0 = ids[2 * t], e1 = ids[2 * t + 1];
    int s0 = atomicAdd(&cur[e0], 1);
    int s1 = atomicAdd(&cur[e1], 1);
    int p0 = meta[16 + e0] + s0;
    int p1 = meta[16 + e1] + s1;
    token_list[p0] = t; pos_list[2 * t] = p0;
    token_list[p1] = t; pos_list[2 * t + 1] = p1;
  }
}

// ---------------- grouped GEMM, single-buffer 2-barrier loop -------------------
// MODE 0: x@w1 + relu^2 -> h1 bf16; MODE 1: h1@w2 (+b2 in kp0) -> h2 partials.
// NW waves arranged WM x (NW/WM); per-wave (BM/WM) x (BN/(NW/WM)) — kept at the
// PROVEN 64x64 per-wave shape (acc 64 VGPR). MAP selects tile map (0: 128-row
// @meta[64]/meta[32]; 1: 256-row @meta[512]/meta[33]).
// LDS: linear rows of BK=64 bf16; 16B k-chunks XOR-swizzled by (row&7) on BOTH
// the global source address (staging) and the ds_read address (rule 21).
// PINNED DECISIONS (each regressed when violated):
//  - min-waves hint = 4 (VGPR cap 128; 5 spilled acc to scratch in R9)
//  - single-buffer LDS (explicit dbuf: R8 -50%; ring-3: R12 -47%)
//  - overlap comes from resident waves/CU (m114), not source pipelining
template<int BM, int BN, int MODE, int NW, int WM, int NKP, int MAP>
__global__ __launch_bounds__(NW * 64, 4) void moe_gemm(
    const unsigned short* __restrict__ A,
    const unsigned short* __restrict__ Bw,   // [E][NN][Kdim] bf16 (pre-transposed)
    const float* __restrict__ bias,          // [E][NN]
    const int* __restrict__ token_list,
    const int* __restrict__ meta,
    unsigned short* __restrict__ Cout,
    const int Kdim, const int NN)
{
  const int NY = NN / BN;
  const int wgid = xcd_swizzle(blockIdx.x, gridDim.x);
  const int mt = wgid / (NY * NKP);
  const int slot = wgid - mt * (NY * NKP);
  const int ny = slot % NY;
  const int kp = slot / NY;
  const int nt_total = MAP == 0 ? meta[32] : meta[33];
  if (mt >= nt_total) return;
  const int* tmap = meta + (MAP == 0 ? 64 : 512);
  const int e = tmap[mt * 2], arow0 = tmap[mt * 2 + 1];
  const int ne_end = meta[16 + e] + meta[e];
  const int n0 = ny * BN;
  const int KLEN = Kdim / NKP;
  const int kbeg = kp * KLEN;
  unsigned short* Cp = Cout + (size_t)kp * CAP * NN;

  __shared__ unsigned short lA[BM * BK];
  __shared__ unsigned short lB[BN * BK];

  const int tid = threadIdx.x;
  const int wave = tid >> 6, lane = tid & 63;
  constexpr int WN = NW / WM;               // waves along N
  const int wr = wave / WN, wc = wave % WN;
  constexpr int WROWS = BM / WM;            // per-wave rows (64 in all configs)
  constexpr int WCOLS = BN / WN;            // per-wave cols (64)
  constexpr int FM = WROWS / 16, FN = WCOLS / 16;
  constexpr int NCA = (BM / 8) / NW;        // A 1KB-chunks per wave
  constexpr int NCB = (BN / 8) / NW;        // B chunks per wave

  // swizzled k-offset for staging: logical chunk (lane&7) XOR row-in-8 (lane>>3)&7
  const int kswz = ((lane & 7) ^ ((lane >> 3) & 7)) * 8;

  size_t aSrc[NCA];
#pragma unroll
  for (int i = 0; i < NCA; ++i) {
    int c = wave + i * NW;
    int r = c * 8 + (lane >> 3);
    int grow = (MODE == 0) ? token_list[arow0 + r] : (arow0 + r);
    aSrc[i] = (size_t)grow * Kdim + kbeg + kswz;
  }
  size_t bSrc[NCB];
#pragma unroll
  for (int i = 0; i < NCB; ++i) {
    int c = wave + i * NW;
    int n = n0 + c * 8 + (lane >> 3);
    bSrc[i] = ((size_t)e * NN + n) * Kdim + kbeg + kswz;
  }

  f32x4 acc[FM][FN] = {};

  for (int k0 = 0; k0 < KLEN; k0 += BK) {
#pragma unroll
    for (int i = 0; i < NCA; ++i)
      gload_lds16(A + aSrc[i] + k0, &lA[(wave + i * NW) * 512]);
#pragma unroll
    for (int i = 0; i < NCB; ++i)
      gload_lds16(Bw + bSrc[i] + k0, &lB[(wave + i * NW) * 512]);
    __syncthreads();
#pragma unroll
    for (int kk = 0; kk < BK; kk += 32) {
      bf16x8 af[FM], bfr[FN];
      const int lc = (kk >> 3) + (lane >> 4);   // logical 16B-chunk index 0..7
#pragma unroll
      for (int m2 = 0; m2 < FM; ++m2) {
        int row = wr * WROWS + m2 * 16 + (lane & 15);
        af[m2] = *(const bf16x8*)&lA[row * BK + ((lc ^ (row & 7)) << 3)];
      }
#pragma unroll
      for (int n2 = 0; n2 < FN; ++n2) {
        int row = wc * WCOLS + n2 * 16 + (lane & 15);
        bfr[n2] = *(const bf16x8*)&lB[row * BK + ((lc ^ (row & 7)) << 3)];
      }
#pragma unroll
      for (int m2 = 0; m2 < FM; ++m2)
#pragma unroll
        for (int n2 = 0; n2 < FN; ++n2)
          acc[m2][n2] = __builtin_amdgcn_mfma_f32_16x16x32_bf16(
              af[m2], bfr[n2], acc[m2][n2], 0, 0, 0);
    }
    __syncthreads();
  }

  const float* be = bias + (size_t)e * NN;
#pragma unroll
  for (int m2 = 0; m2 < FM; ++m2) {
    const int lr = wr * WROWS + m2 * 16 + (lane >> 4) * 4;
#pragma unroll
    for (int n2 = 0; n2 < FN; ++n2) {
      const int col = n0 + wc * WCOLS + n2 * 16 + (lane & 15);
      const float bv = (kp == 0) ? be[col] : 0.f;
#pragma unroll
      for (int j = 0; j < 4; ++j) {
        const int arow = arow0 + lr + j;
        if (arow < ne_end) {
          float v = acc[m2][n2][j] + bv;
          if (MODE == 0) { v = fmaxf(v, 0.f); v = v * v; }
          Cp[(size_t)arow * NN + col] = f2bf(v);
        }
      }
    }
  }
}

// ---------------- combine: out[t] = sum_k gates * sum_kp h2_kp[pos] ------------
__global__ __launch_bounds__(256) void combine_kernel(
    const unsigned short* __restrict__ h2, const int* __restrict__ pos_list,
    const float* __restrict__ gates, float* __restrict__ out)
{
  const int wave = threadIdx.x >> 6, lane = threadIdx.x & 63;
  const int t = blockIdx.x * 4 + wave;
  const int p0 = pos_list[2 * t], p1 = pos_list[2 * t + 1];
  const float g0 = gates[2 * t], g1 = gates[2 * t + 1];
  float* o = out + (size_t)t * HD;
#pragma unroll
  for (int i = 0; i < 3; ++i) {
    int h = i * 256 + lane * 4;
    float4 o4 = {0.f, 0.f, 0.f, 0.f};
#pragma unroll
    for (int kp = 0; kp < NKP2; ++kp) {
      const unsigned short* base = h2 + (size_t)kp * CAP * HD;
      ushort4 a = *(const ushort4*)&base[(size_t)p0 * HD + h];
      ushort4 b = *(const ushort4*)&base[(size_t)p1 * HD + h];
      o4.x += g0 * bf2f(a.x) + g1 * bf2f(b.x);
      o4.y += g0 * bf2f(a.y) + g1 * bf2f(b.y);
      o4.z += g0 * bf2f(a.z) + g1 * bf2f(b.z);
      o4.w += g0 * bf2f(a.w) + g1 * bf2f(b.w);
    }
    *(float4*)&o[h] = o4;
  }
}

// -------------------------------- launch ---------------------------------------
extern "C" void kernel_launch(void* const* d_in, const int* in_sizes, int n_in,
                              void* d_out, int out_size, void* d_ws, size_t ws_size,
                              hipStream_t stream)
{
  (void)in_sizes; (void)n_in; (void)ws_size; (void)out_size;
  const float* x  = (const float*)d_in[0];
  const float* rw = (const float*)d_in[1];
  const float* rb = (const float*)d_in[2];
  const float* w1 = (const float*)d_in[3];
  const float* b1 = (const float*)d_in[4];
  const float* w2 = (const float*)d_in[5];
  const float* b2 = (const float*)d_in[6];
  float* out = (float*)d_out;

  char* ws = (char*)d_ws;
  size_t off = 0;
  auto alloc = [&](size_t bytes) {
    off = (off + 255) & ~(size_t)255;
    void* p = ws + off;
    off += bytes;
    return p;
  };
  unsigned short* xb  = (unsigned short*)alloc((size_t)TOK * HD * 2);
  unsigned short* w1t = (unsigned short*)alloc((size_t)E_EXP * FD * HD * 2);
  unsigned short* w2t = (unsigned short*)alloc((size_t)E_EXP * HD * FD * 2);
  unsigned short* h1  = (unsigned short*)alloc((size_t)CAP * FD * 2);
  unsigned short* h2  = (unsigned short*)alloc((size_t)NKP2 * CAP * HD * 2);  // k-partials
  int*   token_list = (int*)alloc(CAP * 4);
  int*   pos_list   = (int*)alloc((size_t)TOK * 2 * 4);
  int*   ids        = (int*)alloc((size_t)TOK * 2 * 4);
  float* gates      = (float*)alloc((size_t)TOK * 2 * 4);
  float* probs      = (float*)alloc((size_t)TOK * 8 * 4);
  int*   meta       = (int*)alloc(1024 * 4);
  char*  ctrl       = (char*)token_list;
  size_t ctrl_bytes = (ws + off) - ctrl;

  hipMemsetAsync(ctrl, 0, ctrl_bytes, stream);

  // prep: router (1024 blocks) + both weight transposes (9216 blocks), merged
  prep_kernel<<<ROUTER_BLOCKS + T1_TILES + T2_TILES, 256, 0, stream>>>(
      x, rw, rb, xb, probs, ids, gates, w1, w1t, w2, w2t);
  stats_scatter_kernel<<<1, 1024, 0, stream>>>(ids, probs, meta,
      token_list, pos_list, out + (size_t)TOK * HD);
  // GEMM1: <=39 m-tiles(256) x 24 n-tiles(128), 8 waves (4Mx2N, 64x64/wave)
  moe_gemm<256, 128, 0, 8, 4, 1, 1><<<39 * (FD / 128), 512, 0, stream>>>(
      xb, w1t, b1, token_list, meta, h1, HD, FD);
  // GEMM2: 71 max m-tiles(128) x 6 n-tiles x 2 k-splits (R7/R11-proven config)
  moe_gemm<128, 128, 1, 4, 2, NKP2, 0><<<71 * (HD / 128) * NKP2, 256, 0, stream>>>(
      h1, w2t, b2, token_list, meta, h2, FD, HD);
  combine_kernel<<<TOK / 4, 256, 0, stream>>>(h2, pos_list, gates, out);
}

// Round 17
// 185.467 us; speedup vs baseline: 1.0442x; 1.0408x over previous
//
#include <hip/hip_runtime.h>
#include <hip/hip_bf16.h>
#include <stdint.h>

#define E_EXP 8
#define TOK   4096
#define HD    768
#define FD    3072
#define BK    64
#define CAP   8320   // 8192 assignments + max per-expert tile padding
#define NKP2  2      // GEMM2 split-K ways (R7/R11-proven; 3 regressed in R10)

typedef __attribute__((ext_vector_type(8))) short bf16x8;
typedef __attribute__((ext_vector_type(4))) float f32x4;

__device__ __forceinline__ unsigned short f2bf(float f) {
  union { float f; unsigned u; } v; v.f = f;
  unsigned r = v.u + 0x7fffu + ((v.u >> 16) & 1u);
  return (unsigned short)(r >> 16);
}
__device__ __forceinline__ float bf2f(unsigned short u) {
  union { unsigned u; float f; } v; v.u = ((unsigned)u) << 16;
  return v.f;
}

__device__ __forceinline__ void gload_lds16(const void* g, void* l) {
  __builtin_amdgcn_global_load_lds(
      (const __attribute__((address_space(1))) unsigned int*)g,
      (__attribute__((address_space(3))) unsigned int*)l, 16, 0, 0);
}

// bijective XCD-chunking swizzle (m204)
__device__ __forceinline__ int xcd_swizzle(int orig, int nwg) {
  int xcd = orig & 7, base = orig >> 3;
  int q = nwg >> 3, r = nwg & 7;
  return (xcd < r ? xcd * (q + 1) : r * (q + 1) + (xcd - r) * q) + base;
}

// ---------------- prep: router (blocks 0..1023) + weight transpose (rest) ------
// R14-measured config (best total 191.2us). R15's occupancy/conflict "fixes"
// were null-to-negative (rule 23: wrong regime — prep is dependency-latency
// bound, not occupancy/conflict bound).
#define TT 64
#define T1_TILES (E_EXP * (FD / TT) * (HD / TT))   // 4608
#define T2_TILES (E_EXP * (HD / TT) * (FD / TT))   // 4608
#define ROUTER_BLOCKS (TOK / 4)                    // 1024
__global__ __launch_bounds__(256) void prep_kernel(
    const float* __restrict__ x, const float* __restrict__ rw,
    const float* __restrict__ rb, unsigned short* __restrict__ xb,
    float* __restrict__ probs, int* __restrict__ ids,
    float* __restrict__ gates,
    const float* __restrict__ w1, unsigned short* __restrict__ w1t,
    const float* __restrict__ w2, unsigned short* __restrict__ w2t)
{
  __shared__ union {
    float lrw[E_EXP * HD];                  // router: [e][h], 24 KB
    unsigned short tile[TT][TT + 4];        // transpose: 8.7 KB
  } sh;

  if (blockIdx.x < ROUTER_BLOCKS) {
    // ---------------- router path ----------------
    for (int i = threadIdx.x; i < E_EXP * HD; i += 256) {
      int h = i >> 3, e = i & 7;
      sh.lrw[e * HD + h] = rw[i];
    }
    __syncthreads();
    const int wave = threadIdx.x >> 6, lane = threadIdx.x & 63;
    const int t = blockIdx.x * 4 + wave;
    const float* xrow = x + (size_t)t * HD;
    float acc[8] = {0, 0, 0, 0, 0, 0, 0, 0};
#pragma unroll
    for (int i = 0; i < HD / 64; ++i) {
      int h = i * 64 + lane;
      float xv = xrow[h];
      xb[(size_t)t * HD + h] = f2bf(xv);
#pragma unroll
      for (int e = 0; e < 8; ++e) acc[e] += xv * sh.lrw[e * HD + h];
    }
#pragma unroll
    for (int d = 1; d < 64; d <<= 1) {
#pragma unroll
      for (int e = 0; e < 8; ++e) acc[e] += __shfl_xor(acc[e], d);
    }
    if (lane == 0) {
      float p[8]; float m = -1e30f, sum = 0.f;
#pragma unroll
      for (int e = 0; e < 8; ++e) { p[e] = acc[e] + rb[e]; m = fmaxf(m, p[e]); }
#pragma unroll
      for (int e = 0; e < 8; ++e) { p[e] = __expf(p[e] - m); sum += p[e]; }
      float inv = 1.f / sum;
#pragma unroll
      for (int e = 0; e < 8; ++e) p[e] *= inv;
      int i1 = 0;
#pragma unroll
      for (int e = 1; e < 8; ++e) if (p[e] > p[i1]) i1 = e;   // ties -> lower idx
      int i2 = (i1 == 0) ? 1 : 0;
#pragma unroll
      for (int e = 0; e < 8; ++e) if (e != i1 && p[e] > p[i2]) i2 = e;
      ids[t * 2] = i1; ids[t * 2 + 1] = i2;
      float den = 1.f / (p[i1] + p[i2] + 1e-9f);
      gates[t * 2] = p[i1] * den; gates[t * 2 + 1] = p[i2] * den;
#pragma unroll
      for (int e = 0; e < 8; ++e) probs[t * 8 + e] = p[e];
    }
    return;
  }

  // ---------------- transpose path ----------------
  int id = blockIdx.x - ROUTER_BLOCKS;
  const float* W; unsigned short* Wt; int Kd, Nd;
  if (id < T1_TILES) {
    W = w1; Wt = w1t; Kd = HD; Nd = FD;
  } else {
    id -= T1_TILES; W = w2; Wt = w2t; Kd = FD; Nd = HD;
  }
  const int nx = Nd / TT, nk = Kd / TT;
  const int e = id / (nx * nk);
  const int rem = id % (nx * nk);
  const int n0 = (rem % nx) * TT, k0 = (rem / nx) * TT;

  const int r0 = threadIdx.x >> 4;        // 0..15
  const int c4 = threadIdx.x & 15;        // float4 index within 64-wide row
#pragma unroll
  for (int i = 0; i < 4; ++i) {
    int kk = r0 + i * 16;
    float4 v = *(const float4*)&W[((size_t)e * Kd + k0 + kk) * Nd + n0 + c4 * 4];
    sh.tile[c4 * 4 + 0][kk] = f2bf(v.x);
    sh.tile[c4 * 4 + 1][kk] = f2bf(v.y);
    sh.tile[c4 * 4 + 2][kk] = f2bf(v.z);
    sh.tile[c4 * 4 + 3][kk] = f2bf(v.w);
  }
  __syncthreads();
  const int n = threadIdx.x >> 2, kc = threadIdx.x & 3;
  unsigned short* dst = Wt + ((size_t)e * Nd + n0 + n) * Kd + k0 + kc * 16;
  bf16x8 a = *(const bf16x8*)&sh.tile[n][kc * 16];
  bf16x8 b = *(const bf16x8*)&sh.tile[n][kc * 16 + 8];
  *(bf16x8*)&dst[0] = a;
  *(bf16x8*)&dst[8] = b;
}

// ---------------- fused stats+scatter (single block, 1024 threads) -------------
// Fully writes meta/token_list's USED range every call (padded tile rows are
// handled by the GEMM's staging clamp — no global memset needed).
__global__ __launch_bounds__(1024) void stats_scatter_kernel(
    const int* __restrict__ ids, const float* __restrict__ probs,
    int* __restrict__ meta, int* __restrict__ token_list,
    int* __restrict__ pos_list, float* __restrict__ loss_out)
{
  __shared__ int cnt[8], top1c[8], cur[8];
  __shared__ float wsum[16][8];
  const int tid = threadIdx.x;
  if (tid < 8) { cnt[tid] = 0; top1c[tid] = 0; cur[tid] = 0; }
  __syncthreads();
  float local[8] = {0, 0, 0, 0, 0, 0, 0, 0};
  for (int t = tid; t < TOK; t += 1024) {
    int e0 = ids[2 * t], e1 = ids[2 * t + 1];
    atomicAdd(&cnt[e0], 1); atomicAdd(&cnt[e1], 1); atomicAdd(&top1c[e0], 1);
    const float4* pr = (const float4*)&probs[(size_t)t * 8];
    float4 a = pr[0], b = pr[1];
    local[0] += a.x; local[1] += a.y; local[2] += a.z; local[3] += a.w;
    local[4] += b.x; local[5] += b.y; local[6] += b.z; local[7] += b.w;
  }
#pragma unroll
  for (int d = 1; d < 64; d <<= 1) {
#pragma unroll
    for (int e = 0; e < 8; ++e) local[e] += __shfl_xor(local[e], d);
  }
  const int wave = tid >> 6, lane = tid & 63;
  if (lane == 0) {
#pragma unroll
    for (int e = 0; e < 8; ++e) wsum[wave][e] = local[e];
  }
  __syncthreads();
  if (tid == 0) {
    int total = 0, nt1 = 0;
    for (int e = 0; e < 8; ++e) {
      int c = cnt[e];
      meta[e] = c;
      meta[16 + e] = total;                     // base
      int t1 = (c + 127) >> 7;
      for (int i = 0; i < t1; ++i) { meta[64 + nt1 * 2] = e; meta[64 + nt1 * 2 + 1] = total + i * 128; ++nt1; }
      total += c;
    }
    meta[32] = nt1;
    float loss = 0.f;
    for (int e = 0; e < 8; ++e) {
      float psum = 0.f;
      for (int w = 0; w < 16; ++w) psum += wsum[w][e];
      loss += ((float)top1c[e] / 4096.f) * (psum / 4096.f);
    }
    loss_out[0] = 0.001f * loss;
  }
  __syncthreads();
  for (int t = tid; t < TOK; t += 1024) {
    int e0 = ids[2 * t], e1 = ids[2 * t + 1];
    int s0 = atomicAdd(&cur[e0], 1);
    int s1 = atomicAdd(&cur[e1], 1);
    int p0 = meta[16 + e0] + s0;
    int p1 = meta[16 + e1] + s1;
    token_list[p0] = t; pos_list[2 * t] = p0;
    token_list[p1] = t; pos_list[2 * t + 1] = p1;
  }
}

// ---------------- grouped GEMM, single-buffer 2-barrier loop (R7/R11 proven) ---
// MODE 0: x@w1 + relu^2 -> h1 bf16; MODE 1: h1@w2 (+b2 in kp0) -> h2 partials.
// NW waves (NW*64 thr), per-wave (BM/2) x (BN/(NW/2)). 1-D grid, decode
// wgid -> (mt, ny, kp) n/k-fastest + bijective XCD chunking. NKP split-K ways;
// partial kp writes Cout + kp*CAP*NN; bias only in kp==0.
// Padded tile rows: staging row index CLAMPED to ne_end-1 (replaces the old
// global memset of token_list; epilogue stores remain guarded by arow<ne_end).
// LDS: linear rows of BK=64 bf16; 16B k-chunks XOR-swizzled by (row&7) on BOTH
// the global source address (staging) and the ds_read address (rule 21).
// PINNED DECISIONS (each regressed when violated):
//  - min-waves hint = 4 (5 spilled acc to scratch: R9, WRITE 49->235MB)
//  - single-buffer 32KB LDS (explicit dbuf 64KB: R8 -50%; ring-3 144KB: R12 -47%)
//  - overlap comes from ~2.4 resident blocks/CU (m114), not source pipelining
//  - 256x128 8-wave geometry: FETCH -12MB but time-null (R16) — keep 128^2
template<int BM, int BN, int MODE, int NW, int NKP>
__global__ __launch_bounds__(NW * 64, 4) void moe_gemm(
    const unsigned short* __restrict__ A,
    const unsigned short* __restrict__ Bw,   // [E][NN][Kdim] bf16 (pre-transposed)
    const float* __restrict__ bias,          // [E][NN]
    const int* __restrict__ token_list,
    const int* __restrict__ meta,
    unsigned short* __restrict__ Cout,
    const int Kdim, const int NN)
{
  const int NY = NN / BN;
  const int wgid = xcd_swizzle(blockIdx.x, gridDim.x);
  const int mt = wgid / (NY * NKP);
  const int slot = wgid - mt * (NY * NKP);
  const int ny = slot % NY;
  const int kp = slot / NY;
  const int nt_total = meta[32];
  if (mt >= nt_total) return;
  const int* tmap = meta + 64;
  const int e = tmap[mt * 2], arow0 = tmap[mt * 2 + 1];
  const int ne_end = meta[16 + e] + meta[e];
  const int n0 = ny * BN;
  const int KLEN = Kdim / NKP;
  const int kbeg = kp * KLEN;
  unsigned short* Cp = Cout + (size_t)kp * CAP * NN;

  __shared__ unsigned short lA[BM * BK];
  __shared__ unsigned short lB[BN * BK];

  const int tid = threadIdx.x;
  const int wave = tid >> 6, lane = tid & 63;
  constexpr int WC_N = NW / 2;              // waves along N
  const int wr = wave / WC_N, wc = wave % WC_N;
  constexpr int WROWS = BM / 2;             // per-wave rows
  constexpr int WCOLS = BN / WC_N;          // per-wave cols
  constexpr int FM = WROWS / 16, FN = WCOLS / 16;
  constexpr int NCA = (BM / 8) / NW;        // A 1KB-chunks per wave
  constexpr int NCB = (BN / 8) / NW;        // B chunks per wave

  // swizzled k-offset for staging: logical chunk (lane&7) XOR row-in-8 (lane>>3)&7
  const int kswz = ((lane & 7) ^ ((lane >> 3) & 7)) * 8;

  size_t aSrc[NCA];
#pragma unroll
  for (int i = 0; i < NCA; ++i) {
    int c = wave + i * NW;
    int r = arow0 + c * 8 + (lane >> 3);
    if (r >= ne_end) r = ne_end - 1;        // clamp padded rows (no memset)
    int grow = (MODE == 0) ? token_list[r] : r;
    aSrc[i] = (size_t)grow * Kdim + kbeg + kswz;
  }
  size_t bSrc[NCB];
#pragma unroll
  for (int i = 0; i < NCB; ++i) {
    int c = wave + i * NW;
    int n = n0 + c * 8 + (lane >> 3);
    bSrc[i] = ((size_t)e * NN + n) * Kdim + kbeg + kswz;
  }

  f32x4 acc[FM][FN] = {};

  for (int k0 = 0; k0 < KLEN; k0 += BK) {
#pragma unroll
    for (int i = 0; i < NCA; ++i)
      gload_lds16(A + aSrc[i] + k0, &lA[(wave + i * NW) * 512]);
#pragma unroll
    for (int i = 0; i < NCB; ++i)
      gload_lds16(Bw + bSrc[i] + k0, &lB[(wave + i * NW) * 512]);
    __syncthreads();
#pragma unroll
    for (int kk = 0; kk < BK; kk += 32) {
      bf16x8 af[FM], bfr[FN];
      const int lc = (kk >> 3) + (lane >> 4);   // logical 16B-chunk index 0..7
#pragma unroll
      for (int m2 = 0; m2 < FM; ++m2) {
        int row = wr * WROWS + m2 * 16 + (lane & 15);
        af[m2] = *(const bf16x8*)&lA[row * BK + ((lc ^ (row & 7)) << 3)];
      }
#pragma unroll
      for (int n2 = 0; n2 < FN; ++n2) {
        int row = wc * WCOLS + n2 * 16 + (lane & 15);
        bfr[n2] = *(const bf16x8*)&lB[row * BK + ((lc ^ (row & 7)) << 3)];
      }
#pragma unroll
      for (int m2 = 0; m2 < FM; ++m2)
#pragma unroll
        for (int n2 = 0; n2 < FN; ++n2)
          acc[m2][n2] = __builtin_amdgcn_mfma_f32_16x16x32_bf16(
              af[m2], bfr[n2], acc[m2][n2], 0, 0, 0);
    }
    __syncthreads();
  }

  const float* be = bias + (size_t)e * NN;
#pragma unroll
  for (int m2 = 0; m2 < FM; ++m2) {
    const int lr = wr * WROWS + m2 * 16 + (lane >> 4) * 4;
#pragma unroll
    for (int n2 = 0; n2 < FN; ++n2) {
      const int col = n0 + wc * WCOLS + n2 * 16 + (lane & 15);
      const float bv = (kp == 0) ? be[col] : 0.f;
#pragma unroll
      for (int j = 0; j < 4; ++j) {
        const int arow = arow0 + lr + j;
        if (arow < ne_end) {
          float v = acc[m2][n2][j] + bv;
          if (MODE == 0) { v = fmaxf(v, 0.f); v = v * v; }
          Cp[(size_t)arow * NN + col] = f2bf(v);
        }
      }
    }
  }
}

// ---------------- combine: out[t] = sum_k gates * sum_kp h2_kp[pos] ------------
__global__ __launch_bounds__(256) void combine_kernel(
    const unsigned short* __restrict__ h2, const int* __restrict__ pos_list,
    const float* __restrict__ gates, float* __restrict__ out)
{
  const int wave = threadIdx.x >> 6, lane = threadIdx.x & 63;
  const int t = blockIdx.x * 4 + wave;
  const int p0 = pos_list[2 * t], p1 = pos_list[2 * t + 1];
  const float g0 = gates[2 * t], g1 = gates[2 * t + 1];
  float* o = out + (size_t)t * HD;
#pragma unroll
  for (int i = 0; i < 3; ++i) {
    int h = i * 256 + lane * 4;
    float4 o4 = {0.f, 0.f, 0.f, 0.f};
#pragma unroll
    for (int kp = 0; kp < NKP2; ++kp) {
      const unsigned short* base = h2 + (size_t)kp * CAP * HD;
      ushort4 a = *(const ushort4*)&base[(size_t)p0 * HD + h];
      ushort4 b = *(const ushort4*)&base[(size_t)p1 * HD + h];
      o4.x += g0 * bf2f(a.x) + g1 * bf2f(b.x);
      o4.y += g0 * bf2f(a.y) + g1 * bf2f(b.y);
      o4.z += g0 * bf2f(a.z) + g1 * bf2f(b.z);
      o4.w += g0 * bf2f(a.w) + g1 * bf2f(b.w);
    }
    *(float4*)&o[h] = o4;
  }
}

// -------------------------------- launch ---------------------------------------
extern "C" void kernel_launch(void* const* d_in, const int* in_sizes, int n_in,
                              void* d_out, int out_size, void* d_ws, size_t ws_size,
                              hipStream_t stream)
{
  (void)in_sizes; (void)n_in; (void)ws_size; (void)out_size;
  const float* x  = (const float*)d_in[0];
  const float* rw = (const float*)d_in[1];
  const float* rb = (const float*)d_in[2];
  const float* w1 = (const float*)d_in[3];
  const float* b1 = (const float*)d_in[4];
  const float* w2 = (const float*)d_in[5];
  const float* b2 = (const float*)d_in[6];
  float* out = (float*)d_out;

  char* ws = (char*)d_ws;
  size_t off = 0;
  auto alloc = [&](size_t bytes) {
    off = (off + 255) & ~(size_t)255;
    void* p = ws + off;
    off += bytes;
    return p;
  };
  unsigned short* xb  = (unsigned short*)alloc((size_t)TOK * HD * 2);
  unsigned short* w1t = (unsigned short*)alloc((size_t)E_EXP * FD * HD * 2);
  unsigned short* w2t = (unsigned short*)alloc((size_t)E_EXP * HD * FD * 2);
  unsigned short* h1  = (unsigned short*)alloc((size_t)CAP * FD * 2);
  unsigned short* h2  = (unsigned short*)alloc((size_t)NKP2 * CAP * HD * 2);  // k-partials
  int*   token_list = (int*)alloc(CAP * 4);
  int*   pos_list   = (int*)alloc((size_t)TOK * 2 * 4);
  int*   ids        = (int*)alloc((size_t)TOK * 2 * 4);
  float* gates      = (float*)alloc((size_t)TOK * 2 * 4);
  float* probs      = (float*)alloc((size_t)TOK * 8 * 4);
  int*   meta       = (int*)alloc(1024 * 4);

  // prep: router (1024 blocks) + both weight transposes (9216 blocks), merged
  prep_kernel<<<ROUTER_BLOCKS + T1_TILES + T2_TILES, 256, 0, stream>>>(
      x, rw, rb, xb, probs, ids, gates, w1, w1t, w2, w2t);
  stats_scatter_kernel<<<1, 1024, 0, stream>>>(ids, probs, meta,
      token_list, pos_list, out + (size_t)TOK * HD);
  // GEMM1: 71 max m-tiles x 24 n-tiles, 4-wave blocks (64x64 per wave)
  moe_gemm<128, 128, 0, 4, 1><<<71 * (FD / 128), 256, 0, stream>>>(
      xb, w1t, b1, token_list, meta, h1, HD, FD);
  // GEMM2: 71 max m-tiles x 6 n-tiles x 2 k-splits (R7/R11-proven config)
  moe_gemm<128, 128, 1, 4, NKP2><<<71 * (HD / 128) * NKP2, 256, 0, stream>>>(
      h1, w2t, b2, token_list, meta, h2, FD, HD);
  combine_kernel<<<TOK / 4, 256, 0, stream>>>(h2, pos_list, gates, out);
}